// Round 1
// baseline (729.296 us; speedup 1.0000x reference)
//
#include <hip/hip_runtime.h>

// FeatureRefine (rotated-bbox bilinear refine), MI355X / gfx950.
// features: [N=4, C=256, H=128, W=128] fp32 ; bboxes: [N,H,W,5] fp32
// out = features + sum_p bilinear(features, point_p)  (NCHW)
//
// Mapping: block = 256 thr = 4 waves. lane (tid&63) -> w within 64-wide strip
// (coalesced direct load/store); wave (tid>>6) -> channel; each thread computes
// its pixel's sample geometry ONCE (10 offsets + 20 weights in regs, validity
// and border-snap folded into weights) then sweeps 16 channels.

#define N_ 4
#define C_ 256
#define H_ 128
#define W_ 128
#define HW_ (H_ * W_)
#define SCALE 0.125f

__global__ __launch_bounds__(256) void fr_kernel(
    const float* __restrict__ feat,
    const float* __restrict__ bb,
    float* __restrict__ out)
{
    const int lane = threadIdx.x & 63;
    const int wave = threadIdx.x >> 6;
    const int tile = blockIdx.x;            // [0, N*H*(W/64)) = [0,1024)
    const int wt   = tile & 1;              // W/64 = 2 strips
    const int h    = (tile >> 1) & (H_ - 1);
    const int n    = tile >> 8;
    const int w    = wt * 64 + lane;
    const int cb   = blockIdx.y;            // channel block, 0..3 (64 ch each)

    // ---- per-pixel geometry (once per thread, reused over 16 channels) ----
    const float* b = bb + (size_t)((n * H_ + h) * W_ + w) * 5;
    const float cx = b[0], cy = b[1], bw = b[2], bh = b[3], th = b[4];
    const float st = sinf(th), ct = cosf(th);
    const float vx = bw * ct * 0.5f, vy = bw * st * 0.5f;
    const float wx = -bh * st * 0.5f, wy = bh * ct * 0.5f;

    const float pxs[5] = {cx, cx + vx + wx, cx - vx + wx, cx - vx - wx, cx + vx - wx};
    const float pys[5] = {cy, cy + vy + wy, cy - vy + wy, cy - vy - wy, cy + vy - wy};

    int   off0[5], off1[5];
    float wgt[20];
#pragma unroll
    for (int p = 0; p < 5; ++p) {
        float x = pxs[p] * SCALE;
        float y = pys[p] * SCALE;
        const bool valid = (y >= -1.0f) && (y <= (float)H_) &&
                           (x >= -1.0f) && (x <= (float)W_);
        y = fmaxf(y, 0.0f);
        x = fmaxf(x, 0.0f);
        int yl = min((int)y, H_ - 1);   // y >= 0, so (int) == floor
        int xl = min((int)x, W_ - 1);
        if (yl >= H_ - 1) y = (float)yl;   // mmcv border snap: ly = 0
        if (xl >= W_ - 1) x = (float)xl;   // mmcv border snap: lx = 0
        const int yh = min(yl + 1, H_ - 1);
        const float ly = y - (float)yl, lx = x - (float)xl;
        const float hy = 1.0f - ly,     hx = 1.0f - lx;
        // pair base: load (xa, xa+1); when xl==W-1 both corners sit at pair.y
        const int xa = min(xl, W_ - 2);
        float wA, wB;
        if (xl < W_ - 1) { wA = hx; wB = lx; }
        else             { wA = 0.0f; wB = 1.0f; }  // hx=1, lx=0 here
        const float v = valid ? 1.0f : 0.0f;
        off0[p] = yl * W_ + xa;
        off1[p] = yh * W_ + xa;
        wgt[p * 4 + 0] = v * hy * wA;
        wgt[p * 4 + 1] = v * hy * wB;
        wgt[p * 4 + 2] = v * ly * wA;
        wgt[p * 4 + 3] = v * ly * wB;
    }

    // ---- channel sweep: wave handles 16 consecutive channels ----
    const int hw = h * W_ + w;
    const size_t planeBase = ((size_t)n * C_ + cb * 64 + wave * 16) * HW_;
    const float* fp = feat + planeBase;
    float*       op = out  + planeBase;

    for (int it = 0; it < 16; ++it) {
        float acc = fp[hw];
#pragma unroll
        for (int p = 0; p < 5; ++p) {
            acc += wgt[p * 4 + 0] * fp[off0[p]]
                 + wgt[p * 4 + 1] * fp[off0[p] + 1]
                 + wgt[p * 4 + 2] * fp[off1[p]]
                 + wgt[p * 4 + 3] * fp[off1[p] + 1];
        }
        op[hw] = acc;
        fp += HW_;
        op += HW_;
    }
}

extern "C" void kernel_launch(void* const* d_in, const int* in_sizes, int n_in,
                              void* d_out, int out_size, void* d_ws, size_t ws_size,
                              hipStream_t stream) {
    const float* feat = (const float*)d_in[0];   // [N,C,H,W]
    const float* bbox = (const float*)d_in[1];   // [N,H,W,5]
    float* out = (float*)d_out;                  // [N,C,H,W]

    dim3 grid(N_ * H_ * (W_ / 64), C_ / 64, 1);  // 1024 x 4 blocks
    fr_kernel<<<grid, dim3(256, 1, 1), 0, stream>>>(feat, bbox, out);
}

// Round 2
// 282.190 us; speedup vs baseline: 2.5844x; 2.5844x over previous
//
#include <hip/hip_runtime.h>

// FeatureRefine, MI355X/gfx950 — round 2: NHWC gather layout.
// R1 was address-divergence bound (random per-pixel samples, lane=w, NCHW ->
// 64 lines per gather instruction; VALUBusy 4.8%, HBM 6%). Fix: transpose to
// NHWC in d_ws, gather with lane=channel (256B contiguous per corner fetch),
// transpose output back through padded LDS tile.

#define N_ 4
#define C_ 256
#define H_ 128
#define W_ 128
#define HW_ (H_ * W_)
#define SCALE 0.125f

// ---------------- Pass 1: NCHW -> NHWC tiled transpose ----------------
__global__ __launch_bounds__(256) void nchw2nhwc(const float* __restrict__ in,
                                                 float* __restrict__ out)
{
    __shared__ float tile[64 * 65];
    const int t   = threadIdx.x;
    const int l   = t & 63;
    const int g   = t >> 6;
    const int hw0 = blockIdx.x * 64;
    const int c0  = blockIdx.y * 64;
    const int n   = blockIdx.z;
#pragma unroll
    for (int rr = 0; rr < 16; ++rr) {
        const int cl = rr * 4 + g;
        tile[l * 65 + cl] = in[(size_t)(n * C_ + c0 + cl) * HW_ + hw0 + l];
    }
    __syncthreads();
#pragma unroll
    for (int rr = 0; rr < 16; ++rr) {
        const int hwl = rr * 4 + g;
        out[(size_t)(n * HW_ + hw0 + hwl) * C_ + c0 + l] = tile[hwl * 65 + l];
    }
}

// ---------------- Pass 2: refine with channel-coalesced gathers ----------------
// Block: 256 thr = 4 waves. Block owns 32 pixels (n, h, w0..w0+31).
// wave = channel quarter (lane -> channel). Geometry computed once per pixel
// by threads t<32, shared via LDS (SoA: off0[5], off1[5], 4x weights[5]).
__global__ __launch_bounds__(256) void fr_refine(const float* __restrict__ nhwc,
                                                 const float* __restrict__ bb,
                                                 float* __restrict__ out)
{
    __shared__ float geo[32 * 32];        // 32 px * 32 words (30 used)
    __shared__ float tile[C_ * 17];       // 256 ch x 16 px, pad 17 (conflict-free)

    const int t    = threadIdx.x;
    const int lane = t & 63;
    const int cc   = t >> 6;
    const int bx   = blockIdx.x;          // [0, 2048)
    const int wq   = bx & 3;              // W quarter (32 px)
    const int h    = (bx >> 2) & (H_ - 1);
    const int n    = bx >> 9;
    const int w0   = wq * 32;

    // ---- geometry: one thread per pixel ----
    if (t < 32) {
        const int w = w0 + t;
        const float* b = bb + (size_t)((n * H_ + h) * W_ + w) * 5;
        const float cx = b[0], cy = b[1], bw = b[2], bh = b[3], th = b[4];
        const float st = sinf(th), ct = cosf(th);
        const float vx = bw * ct * 0.5f, vy = bw * st * 0.5f;
        const float wx = -bh * st * 0.5f, wy = bh * ct * 0.5f;
        const float pxs[5] = {cx, cx + vx + wx, cx - vx + wx, cx - vx - wx, cx + vx - wx};
        const float pys[5] = {cy, cy + vy + wy, cy - vy + wy, cy - vy - wy, cy + vy - wy};
        float* gp = &geo[t * 32];
#pragma unroll
        for (int p = 0; p < 5; ++p) {
            float x = pxs[p] * SCALE;
            float y = pys[p] * SCALE;
            const bool valid = (y >= -1.0f) && (y <= (float)H_) &&
                               (x >= -1.0f) && (x <= (float)W_);
            y = fmaxf(y, 0.0f);
            x = fmaxf(x, 0.0f);
            int yl = min((int)y, H_ - 1);
            int xl = min((int)x, W_ - 1);
            if (yl >= H_ - 1) y = (float)yl;   // mmcv border snap
            if (xl >= W_ - 1) x = (float)xl;
            const int yh = min(yl + 1, H_ - 1);
            const float ly = y - (float)yl, lx = x - (float)xl;
            const float hy = 1.0f - ly,     hx = 1.0f - lx;
            const int xa = min(xl, W_ - 2); // pair base: corners at xa, xa+1
            float wA, wB;
            if (xl < W_ - 1) { wA = hx; wB = lx; }
            else             { wA = 0.0f; wB = 1.0f; }
            const float v = valid ? 1.0f : 0.0f;
            gp[p]      = __int_as_float(yl * W_ + xa);
            gp[5 + p]  = __int_as_float(yh * W_ + xa);
            gp[10 + p] = v * hy * wA;
            gp[15 + p] = v * hy * wB;
            gp[20 + p] = v * ly * wA;
            gp[25 + p] = v * ly * wB;
        }
        gp[30] = 0.0f; gp[31] = 0.0f;
    }
    __syncthreads();

    // plane base for this n, this wave's channel quarter
    const float* pl  = nhwc + (size_t)n * HW_ * C_ + cc * 64 + lane;
    const float* pld = pl + (size_t)(h * W_ + w0) * C_;   // direct reads

    for (int g16 = 0; g16 < 2; ++g16) {
#pragma unroll
        for (int p = 0; p < 16; ++p) {
            const int px = g16 * 16 + p;
            // wave-uniform broadcast read of pixel geometry
            const float4* gp4 = (const float4*)&geo[px * 32];
            float4 Gv[8];
#pragma unroll
            for (int k = 0; k < 8; ++k) Gv[k] = gp4[k];
            const float* gg = (const float*)Gv;

            float acc = pld[(size_t)px * C_];
#pragma unroll
            for (int q = 0; q < 5; ++q) {
                const int o0 = __float_as_int(gg[q]);
                const int o1 = __float_as_int(gg[5 + q]);
                acc = fmaf(gg[10 + q], pl[(size_t)o0 * C_], acc);
                acc = fmaf(gg[15 + q], pl[(size_t)o0 * C_ + C_], acc);
                acc = fmaf(gg[20 + q], pl[(size_t)o1 * C_], acc);
                acc = fmaf(gg[25 + q], pl[(size_t)o1 * C_ + C_], acc);
            }
            tile[(cc * 64 + lane) * 17 + p] = acc;
        }
        __syncthreads();
        // flush 256ch x 16px to NCHW, line-dense (4 c-rows x 16 w per store)
#pragma unroll
        for (int it = 0; it < 16; ++it) {
            const int flat = it * 256 + t;
            const int c  = flat >> 4;
            const int wl = flat & 15;
            out[((size_t)(n * C_ + c) * H_ + h) * W_ + w0 + g16 * 16 + wl] =
                tile[c * 17 + wl];
        }
        __syncthreads();
    }
}

// ---------------- Fallback (round-1 kernel) if ws too small ----------------
__global__ __launch_bounds__(256) void fr_kernel(
    const float* __restrict__ feat,
    const float* __restrict__ bb,
    float* __restrict__ out)
{
    const int lane = threadIdx.x & 63;
    const int wave = threadIdx.x >> 6;
    const int tile = blockIdx.x;
    const int wt   = tile & 1;
    const int h    = (tile >> 1) & (H_ - 1);
    const int n    = tile >> 8;
    const int w    = wt * 64 + lane;
    const int cb   = blockIdx.y;

    const float* b = bb + (size_t)((n * H_ + h) * W_ + w) * 5;
    const float cx = b[0], cy = b[1], bw = b[2], bh = b[3], th = b[4];
    const float st = sinf(th), ct = cosf(th);
    const float vx = bw * ct * 0.5f, vy = bw * st * 0.5f;
    const float wx = -bh * st * 0.5f, wy = bh * ct * 0.5f;
    const float pxs[5] = {cx, cx + vx + wx, cx - vx + wx, cx - vx - wx, cx + vx - wx};
    const float pys[5] = {cy, cy + vy + wy, cy - vy + wy, cy - vy - wy, cy + vy - wy};

    int   off0[5], off1[5];
    float wgt[20];
#pragma unroll
    for (int p = 0; p < 5; ++p) {
        float x = pxs[p] * SCALE;
        float y = pys[p] * SCALE;
        const bool valid = (y >= -1.0f) && (y <= (float)H_) &&
                           (x >= -1.0f) && (x <= (float)W_);
        y = fmaxf(y, 0.0f);
        x = fmaxf(x, 0.0f);
        int yl = min((int)y, H_ - 1);
        int xl = min((int)x, W_ - 1);
        if (yl >= H_ - 1) y = (float)yl;
        if (xl >= W_ - 1) x = (float)xl;
        const int yh = min(yl + 1, H_ - 1);
        const float ly = y - (float)yl, lx = x - (float)xl;
        const float hy = 1.0f - ly,     hx = 1.0f - lx;
        const int xa = min(xl, W_ - 2);
        float wA, wB;
        if (xl < W_ - 1) { wA = hx; wB = lx; }
        else             { wA = 0.0f; wB = 1.0f; }
        const float v = valid ? 1.0f : 0.0f;
        off0[p] = yl * W_ + xa;
        off1[p] = yh * W_ + xa;
        wgt[p * 4 + 0] = v * hy * wA;
        wgt[p * 4 + 1] = v * hy * wB;
        wgt[p * 4 + 2] = v * ly * wA;
        wgt[p * 4 + 3] = v * ly * wB;
    }

    const int hw = h * W_ + w;
    const size_t planeBase = ((size_t)n * C_ + cb * 64 + wave * 16) * HW_;
    const float* fp = feat + planeBase;
    float*       op = out  + planeBase;
    for (int it = 0; it < 16; ++it) {
        float acc = fp[hw];
#pragma unroll
        for (int p = 0; p < 5; ++p) {
            acc += wgt[p * 4 + 0] * fp[off0[p]]
                 + wgt[p * 4 + 1] * fp[off0[p] + 1]
                 + wgt[p * 4 + 2] * fp[off1[p]]
                 + wgt[p * 4 + 3] * fp[off1[p] + 1];
        }
        op[hw] = acc;
        fp += HW_;
        op += HW_;
    }
}

extern "C" void kernel_launch(void* const* d_in, const int* in_sizes, int n_in,
                              void* d_out, int out_size, void* d_ws, size_t ws_size,
                              hipStream_t stream) {
    const float* feat = (const float*)d_in[0];   // [N,C,H,W]
    const float* bbox = (const float*)d_in[1];   // [N,H,W,5]
    float* out = (float*)d_out;                  // [N,C,H,W]

    const size_t need = (size_t)N_ * C_ * HW_ * sizeof(float);  // 64 MB NHWC
    if (ws_size >= need) {
        float* nhwc = (float*)d_ws;
        nchw2nhwc<<<dim3(HW_ / 64, C_ / 64, N_), dim3(256), 0, stream>>>(feat, nhwc);
        fr_refine<<<dim3(N_ * H_ * (W_ / 32)), dim3(256), 0, stream>>>(nhwc, bbox, out);
    } else {
        dim3 grid(N_ * H_ * (W_ / 64), C_ / 64, 1);
        fr_kernel<<<grid, dim3(256), 0, stream>>>(feat, bbox, out);
    }
}

// Round 3
// 204.772 us; speedup vs baseline: 3.5615x; 1.3781x over previous
//
#include <hip/hip_runtime.h>

// FeatureRefine, MI355X/gfx950 — round 3.
// R2: refine was HBM-random-granularity bound (FETCH 571 MB, 3.46 TB/s, VALU 17%),
// transpose was scatter-write bound (~94 us). Changes:
//  1. bf16 NHWC gather plane (ushort2 = 2ch/lane): halves request volume + footprint.
//  2. geometry pre-kernel -> 128 B/px records in d_ws, read via wave-uniform s_load;
//     weights/offsets in SGPRs, gathers become saddr+lane loads (no VALU addr math).
//  3. transpose: block = 64hw x 256c, contiguous 32 KB NHWC bf16 writes.
//  4. XCD-batch swizzle (bx&7 -> batch) so each XCD L2 caches one 8 MB plane.
// Identity term added exactly from fp32 NCHW in the flush phase.

#define N_ 4
#define C_ 256
#define H_ 128
#define W_ 128
#define HW_ (H_ * W_)
#define SCALE 0.125f

typedef unsigned int uint32;
typedef unsigned short ushort16;

__device__ __forceinline__ ushort16 f2bf(float f) {
    uint32 u = __float_as_uint(f);
    u = (u + 0x7FFF + ((u >> 16) & 1)) >> 16;   // RNE
    return (ushort16)u;
}
__device__ __forceinline__ float blo(uint32 u) { return __uint_as_float(u << 16); }
__device__ __forceinline__ float bhi(uint32 u) { return __uint_as_float(u & 0xFFFF0000u); }

// ---------- Pass 0: per-pixel geometry records (32 uints = 128 B each) ----------
// layout per px: [0..4]=off0[q], [5..9]=off1[q], [10..14]=w00, [15..19]=w01,
//                [20..24]=w10, [25..29]=w11, [30..31]=pad
__global__ __launch_bounds__(256) void geo_kernel(const float* __restrict__ bb,
                                                  uint32* __restrict__ geoG)
{
    const int px = blockIdx.x * 256 + threadIdx.x;   // [0, N*H*W)
    const float* b = bb + (size_t)px * 5;
    const float cx = b[0], cy = b[1], bw = b[2], bh = b[3], th = b[4];
    const float st = sinf(th), ct = cosf(th);
    const float vx = bw * ct * 0.5f, vy = bw * st * 0.5f;
    const float wx = -bh * st * 0.5f, wy = bh * ct * 0.5f;
    const float pxs[5] = {cx, cx + vx + wx, cx - vx + wx, cx - vx - wx, cx + vx - wx};
    const float pys[5] = {cy, cy + vy + wy, cy - vy + wy, cy - vy - wy, cy + vy - wy};

    uint32* g = geoG + (size_t)px * 32;
#pragma unroll
    for (int p = 0; p < 5; ++p) {
        float x = pxs[p] * SCALE;
        float y = pys[p] * SCALE;
        const bool valid = (y >= -1.0f) && (y <= (float)H_) &&
                           (x >= -1.0f) && (x <= (float)W_);
        y = fmaxf(y, 0.0f);
        x = fmaxf(x, 0.0f);
        int yl = min((int)y, H_ - 1);
        int xl = min((int)x, W_ - 1);
        if (yl >= H_ - 1) y = (float)yl;   // mmcv border snap: ly = 0
        if (xl >= W_ - 1) x = (float)xl;   // lx = 0
        const int yh = min(yl + 1, H_ - 1);
        const float ly = y - (float)yl, lx = x - (float)xl;
        const float hy = 1.0f - ly,     hx = 1.0f - lx;
        const int xa = min(xl, W_ - 2);    // load corners (xa, xa+1)
        float wA, wB;
        if (xl < W_ - 1) { wA = hx; wB = lx; }
        else             { wA = 0.0f; wB = 1.0f; }
        const float v = valid ? 1.0f : 0.0f;
        g[p]      = (uint32)(yl * W_ + xa);
        g[5 + p]  = (uint32)(yh * W_ + xa);
        g[10 + p] = __float_as_uint(v * hy * wA);
        g[15 + p] = __float_as_uint(v * hy * wB);
        g[20 + p] = __float_as_uint(v * ly * wA);
        g[25 + p] = __float_as_uint(v * ly * wB);
    }
    g[30] = 0u; g[31] = 0u;
}

// ---------- Pass 1: NCHW fp32 -> NHWC bf16, contiguous writes ----------
// block = 64 hw x 256 c; writes one contiguous 32 KB NHWC span.
__global__ __launch_bounds__(256) void nchw2nhwc_bf16(const float* __restrict__ in,
                                                      uint32* __restrict__ outU)
{
    __shared__ ushort16 tile[64 * 258];   // [hw][c], pad 258 (33 KB)
    const int t   = threadIdx.x;
    const int l   = t & 63;               // hw lane
    const int g   = t >> 6;               // wave -> c stripe
    const int hw0 = blockIdx.x * 64;
    const int n   = blockIdx.y;
    const size_t inBase = (size_t)n * C_ * HW_ + hw0;
#pragma unroll 8
    for (int it = 0; it < 64; ++it) {
        const int c = it * 4 + g;
        tile[l * 258 + c] = f2bf(in[inBase + (size_t)c * HW_ + l]);
    }
    __syncthreads();
    // write 2 rows (512 B each) per iteration: waves 0-1 row A, waves 2-3 row A+1
#pragma unroll 8
    for (int it = 0; it < 32; ++it) {
        const int row = it * 2 + (t >> 7);
        const int q   = t & 127;          // uint index within row (2 ch each)
        const uint32 val = *(const uint32*)&tile[row * 258 + q * 2];
        outU[((size_t)n * HW_ + hw0 + row) * 128 + q] = val;
    }
}

// ---------- Pass 2: refine ----------
// block = 256 thr; wavepair wp owns 16 px (all 256 ch via 128 lanes x ushort2).
// Geometry via wave-uniform s_load; gathers: scalar base + lane offset.
__global__ __launch_bounds__(256) void fr_refine(const uint32* __restrict__ nhwcU,
                                                 const uint32* __restrict__ geoG,
                                                 const float* __restrict__ feat,
                                                 float* __restrict__ out)
{
    __shared__ float tile[C_ * 33];       // [c][px], 33.8 KB
    const int t  = threadIdx.x;
    const int bx = blockIdx.x;            // [0, 2048)
    // XCD-batch swizzle: xcd = bx & 7 -> batch n = xcd>>1 (each XCD: one 8 MB plane)
    const int xcd = bx & 7;
    const int n   = xcd >> 1;
    const int idx = ((bx >> 3) << 1) | (xcd & 1);   // [0, 512)
    const int h   = idx >> 2;
    const int w0  = (idx & 3) * 32;

    const int wp = __builtin_amdgcn_readfirstlane(t >> 7);  // wave-uniform px half
    const int j  = t & 127;                                  // ch pair: 2j, 2j+1

    const uint32* plane = nhwcU + (size_t)n * HW_ * 128 + j;
    const uint32* gbase = geoG +
        (size_t)((n * H_ + h) * W_ + w0 + wp * 16) * 32;

    float ax[16], ay[16];
#pragma unroll
    for (int p = 0; p < 16; ++p) { ax[p] = 0.0f; ay[p] = 0.0f; }

#pragma unroll 4
    for (int p = 0; p < 16; ++p) {
        const uint32* g = gbase + p * 32;   // uniform -> s_load
#pragma unroll
        for (int q = 0; q < 5; ++q) {
            const int o0 = (int)g[q];
            const int o1 = (int)g[5 + q];
            const float w00 = __uint_as_float(g[10 + q]);
            const float w01 = __uint_as_float(g[15 + q]);
            const float w10 = __uint_as_float(g[20 + q]);
            const float w11 = __uint_as_float(g[25 + q]);
            const uint32 A = plane[(size_t)o0 * 128];
            const uint32 B = plane[(size_t)o0 * 128 + 128];
            const uint32 Cv = plane[(size_t)o1 * 128];
            const uint32 D = plane[(size_t)o1 * 128 + 128];
            ax[p] = fmaf(w00, blo(A), ax[p]);  ay[p] = fmaf(w00, bhi(A), ay[p]);
            ax[p] = fmaf(w01, blo(B), ax[p]);  ay[p] = fmaf(w01, bhi(B), ay[p]);
            ax[p] = fmaf(w10, blo(Cv), ax[p]); ay[p] = fmaf(w10, bhi(Cv), ay[p]);
            ax[p] = fmaf(w11, blo(D), ax[p]);  ay[p] = fmaf(w11, bhi(D), ay[p]);
        }
    }
#pragma unroll
    for (int p = 0; p < 16; ++p) {
        const int px = wp * 16 + p;
        tile[(2 * j) * 33 + px]     = ax[p];
        tile[(2 * j + 1) * 33 + px] = ay[p];
    }
    __syncthreads();
    // flush: out = feat (exact fp32, coalesced NCHW) + gather sum
    const size_t obase = (size_t)n * C_ * HW_ + h * W_ + w0;
#pragma unroll 4
    for (int it = 0; it < 32; ++it) {
        const int flat = it * 256 + t;    // 256 c x 32 w
        const int c  = flat >> 5;
        const int wl = flat & 31;
        const size_t a = obase + (size_t)c * HW_ + wl;
        out[a] = feat[a] + tile[c * 33 + wl];
    }
}

// ---------- Fallback (round-1 kernel) if ws too small ----------
__global__ __launch_bounds__(256) void fr_kernel(
    const float* __restrict__ feat,
    const float* __restrict__ bb,
    float* __restrict__ out)
{
    const int lane = threadIdx.x & 63;
    const int wave = threadIdx.x >> 6;
    const int tile = blockIdx.x;
    const int wt   = tile & 1;
    const int h    = (tile >> 1) & (H_ - 1);
    const int n    = tile >> 8;
    const int w    = wt * 64 + lane;
    const int cb   = blockIdx.y;

    const float* b = bb + (size_t)((n * H_ + h) * W_ + w) * 5;
    const float cx = b[0], cy = b[1], bw = b[2], bh = b[3], th = b[4];
    const float st = sinf(th), ct = cosf(th);
    const float vx = bw * ct * 0.5f, vy = bw * st * 0.5f;
    const float wx = -bh * st * 0.5f, wy = bh * ct * 0.5f;
    const float pxs[5] = {cx, cx + vx + wx, cx - vx + wx, cx - vx - wx, cx + vx - wx};
    const float pys[5] = {cy, cy + vy + wy, cy - vy + wy, cy - vy - wy, cy + vy - wy};

    int   off0[5], off1[5];
    float wgt[20];
#pragma unroll
    for (int p = 0; p < 5; ++p) {
        float x = pxs[p] * SCALE;
        float y = pys[p] * SCALE;
        const bool valid = (y >= -1.0f) && (y <= (float)H_) &&
                           (x >= -1.0f) && (x <= (float)W_);
        y = fmaxf(y, 0.0f);
        x = fmaxf(x, 0.0f);
        int yl = min((int)y, H_ - 1);
        int xl = min((int)x, W_ - 1);
        if (yl >= H_ - 1) y = (float)yl;
        if (xl >= W_ - 1) x = (float)xl;
        const int yh = min(yl + 1, H_ - 1);
        const float ly = y - (float)yl, lx = x - (float)xl;
        const float hy = 1.0f - ly,     hx = 1.0f - lx;
        const int xa = min(xl, W_ - 2);
        float wA, wB;
        if (xl < W_ - 1) { wA = hx; wB = lx; }
        else             { wA = 0.0f; wB = 1.0f; }
        const float v = valid ? 1.0f : 0.0f;
        off0[p] = yl * W_ + xa;
        off1[p] = yh * W_ + xa;
        wgt[p * 4 + 0] = v * hy * wA;
        wgt[p * 4 + 1] = v * hy * wB;
        wgt[p * 4 + 2] = v * ly * wA;
        wgt[p * 4 + 3] = v * ly * wB;
    }

    const int hw = h * W_ + w;
    const size_t planeBase = ((size_t)n * C_ + cb * 64 + wave * 16) * HW_;
    const float* fp = feat + planeBase;
    float*       op = out  + planeBase;
    for (int it = 0; it < 16; ++it) {
        float acc = fp[hw];
#pragma unroll
        for (int p = 0; p < 5; ++p) {
            acc += wgt[p * 4 + 0] * fp[off0[p]]
                 + wgt[p * 4 + 1] * fp[off0[p] + 1]
                 + wgt[p * 4 + 2] * fp[off1[p]]
                 + wgt[p * 4 + 3] * fp[off1[p] + 1];
        }
        op[hw] = acc;
        fp += HW_;
        op += HW_;
    }
}

extern "C" void kernel_launch(void* const* d_in, const int* in_sizes, int n_in,
                              void* d_out, int out_size, void* d_ws, size_t ws_size,
                              hipStream_t stream) {
    const float* feat = (const float*)d_in[0];   // [N,C,H,W] fp32
    const float* bbox = (const float*)d_in[1];   // [N,H,W,5] fp32
    float* out = (float*)d_out;

    const size_t nhwcBytes = (size_t)N_ * HW_ * C_ * 2;        // 32 MB bf16
    const size_t geoBytes  = (size_t)N_ * HW_ * 32 * 4;        // 8 MB
    if (ws_size >= nhwcBytes + geoBytes) {
        uint32* nhwcU = (uint32*)d_ws;
        uint32* geoG  = (uint32*)((char*)d_ws + nhwcBytes);
        geo_kernel<<<dim3(N_ * HW_ / 256), dim3(256), 0, stream>>>(bbox, geoG);
        nchw2nhwc_bf16<<<dim3(HW_ / 64, N_), dim3(256), 0, stream>>>(feat, nhwcU);
        fr_refine<<<dim3(N_ * H_ * (W_ / 32)), dim3(256), 0, stream>>>(nhwcU, geoG, feat, out);
    } else {
        dim3 grid(N_ * H_ * (W_ / 64), C_ / 64, 1);
        fr_kernel<<<grid, dim3(256), 0, stream>>>(feat, bbox, out);
    }
}

// Round 4
// 179.099 us; speedup vs baseline: 4.0720x; 1.1433x over previous
//
#include <hip/hip_runtime.h>

// FeatureRefine, MI355X/gfx950 — round 4.
// R3: refine 93us (FETCH 218MB, 2.6M x 256B gather loads), transpose ~78us
// (256B-granule reads). Changes:
//  1. refine: wave-per-pixel; corner row-pair = ONE dwordx4 wave-load (1KB
//     contiguous: lanes 0-31 = corner A's 256ch, 32-63 = corner B). 4x fewer
//     vmem insts. Partial sums combined via shfl_xor(32). Identity taken from
//     bf16 NHWC (drops 64MB fp32 feat re-read). [px][c] LDS tile, b128 writes.
//  2. transpose: 512thr, 128hw x 256c tile, 512B-granule reads AND writes.

#define N_ 4
#define C_ 256
#define H_ 128
#define W_ 128
#define HW_ (H_ * W_)
#define SCALE 0.125f

typedef unsigned int uint32;

__device__ __forceinline__ uint32 f2bf(float f) {
    uint32 u = __float_as_uint(f);
    u = (u + 0x7FFF + ((u >> 16) & 1)) >> 16;   // RNE
    return u;
}
__device__ __forceinline__ float blo(uint32 u) { return __uint_as_float(u << 16); }
__device__ __forceinline__ float bhi(uint32 u) { return __uint_as_float(u & 0xFFFF0000u); }

// ---------- Pass 0: per-pixel geometry records (32 uints = 128 B each) ----------
__global__ __launch_bounds__(256) void geo_kernel(const float* __restrict__ bb,
                                                  uint32* __restrict__ geoG)
{
    const int px = blockIdx.x * 256 + threadIdx.x;
    const float* b = bb + (size_t)px * 5;
    const float cx = b[0], cy = b[1], bw = b[2], bh = b[3], th = b[4];
    const float st = sinf(th), ct = cosf(th);
    const float vx = bw * ct * 0.5f, vy = bw * st * 0.5f;
    const float wx = -bh * st * 0.5f, wy = bh * ct * 0.5f;
    const float pxs[5] = {cx, cx + vx + wx, cx - vx + wx, cx - vx - wx, cx + vx - wx};
    const float pys[5] = {cy, cy + vy + wy, cy - vy + wy, cy - vy - wy, cy + vy - wy};

    uint32* g = geoG + (size_t)px * 32;
#pragma unroll
    for (int p = 0; p < 5; ++p) {
        float x = pxs[p] * SCALE;
        float y = pys[p] * SCALE;
        const bool valid = (y >= -1.0f) && (y <= (float)H_) &&
                           (x >= -1.0f) && (x <= (float)W_);
        y = fmaxf(y, 0.0f);
        x = fmaxf(x, 0.0f);
        int yl = min((int)y, H_ - 1);
        int xl = min((int)x, W_ - 1);
        if (yl >= H_ - 1) y = (float)yl;   // mmcv border snap: ly = 0
        if (xl >= W_ - 1) x = (float)xl;   // lx = 0
        const int yh = min(yl + 1, H_ - 1);
        const float ly = y - (float)yl, lx = x - (float)xl;
        const float hy = 1.0f - ly,     hx = 1.0f - lx;
        const int xa = min(xl, W_ - 2);
        float wA, wB;
        if (xl < W_ - 1) { wA = hx; wB = lx; }
        else             { wA = 0.0f; wB = 1.0f; }
        const float v = valid ? 1.0f : 0.0f;
        g[p]      = (uint32)(yl * W_ + xa);
        g[5 + p]  = (uint32)(yh * W_ + xa);
        g[10 + p] = __float_as_uint(v * hy * wA);
        g[15 + p] = __float_as_uint(v * hy * wB);
        g[20 + p] = __float_as_uint(v * ly * wA);
        g[25 + p] = __float_as_uint(v * ly * wB);
    }
    g[30] = 0u; g[31] = 0u;
}

// ---------- Pass 1: NCHW fp32 -> NHWC bf16 (packed ch-pairs) ----------
// block = 512 thr (8 waves); tile 128 hw x 256 c. Reads: 512B/channel
// (float2 x 64 lanes). Writes: contiguous 512B NHWC rows (uint2 x 64).
__global__ __launch_bounds__(512) void nchw2nhwc_bf16(const float* __restrict__ in,
                                                      uint32* __restrict__ outU)
{
    __shared__ uint32 tile[128 * 130];    // [hw][cpair], stride 130 (65 KB)
    const int t   = threadIdx.x;
    const int l   = t & 63;
    const int g   = t >> 6;               // wave 0..7
    const int hw0 = blockIdx.x * 128;
    const int n   = blockIdx.y;
    const float* base = in + (size_t)n * C_ * HW_ + hw0;
#pragma unroll 4
    for (int i = 0; i < 16; ++i) {
        const int cp = i * 8 + g;         // channel-pair 0..127
        const int c  = cp * 2;
        const float2 v0 = *(const float2*)(base + (size_t)c * HW_ + 2 * l);
        const float2 v1 = *(const float2*)(base + (size_t)(c + 1) * HW_ + 2 * l);
        tile[(2 * l) * 130 + cp]     = f2bf(v0.x) | (f2bf(v1.x) << 16);
        tile[(2 * l + 1) * 130 + cp] = f2bf(v0.y) | (f2bf(v1.y) << 16);
    }
    __syncthreads();
#pragma unroll 4
    for (int i = 0; i < 16; ++i) {
        const int r = i * 8 + g;
        const uint2 v = *(const uint2*)&tile[r * 130 + 2 * l];
        *(uint2*)(outU + ((size_t)n * HW_ + hw0 + r) * 128 + 2 * l) = v;
    }
}

// ---------- Pass 2: refine — wave per pixel ----------
__global__ __launch_bounds__(256) void fr_refine(const uint32* __restrict__ nhwcU,
                                                 const uint32* __restrict__ geoG,
                                                 float* __restrict__ out)
{
    __shared__ float tile[32 * 260];      // [px][c], stride 260 (33 KB)
    const int t  = threadIdx.x;
    const int l  = t & 63;
    const int wv = __builtin_amdgcn_readfirstlane(t >> 6);
    const int bx = blockIdx.x;            // [0, 2048)
    const int xcd = bx & 7;               // XCD-batch swizzle
    const int n   = xcd >> 1;
    const int idx = ((bx >> 3) << 1) | (xcd & 1);
    const int h   = idx >> 2;
    const int w0  = (idx & 3) * 32;

    const float idsel = (l < 32) ? 1.0f : 0.0f;   // identity only in A-half
    const uint32* plane = nhwcU + (size_t)n * HW_ * 128;
    const uint32* gb = geoG + (size_t)((n * H_ + h) * W_ + w0 + wv * 8) * 32;

#pragma unroll 2
    for (int p = 0; p < 8; ++p) {
        const uint32* g = gb + p * 32;    // wave-uniform -> s_load
        const int hwp = h * W_ + w0 + wv * 8 + p;

        float a[8];
        {   // identity from own NHWC row (bf16)
            const uint4 r = *(const uint4*)(plane + (size_t)hwp * 128 + 4 * l);
            a[0] = idsel * blo(r.x); a[1] = idsel * bhi(r.x);
            a[2] = idsel * blo(r.y); a[3] = idsel * bhi(r.y);
            a[4] = idsel * blo(r.z); a[5] = idsel * bhi(r.z);
            a[6] = idsel * blo(r.w); a[7] = idsel * bhi(r.w);
        }
#pragma unroll
        for (int q = 0; q < 5; ++q) {
            const int o0 = (int)g[q];
            const int o1 = (int)g[5 + q];
            const float w00 = __uint_as_float(g[10 + q]);
            const float w01 = __uint_as_float(g[15 + q]);
            const float w10 = __uint_as_float(g[20 + q]);
            const float w11 = __uint_as_float(g[25 + q]);
            const float wr0 = (l < 32) ? w00 : w01;   // row0: A | B corner
            const float wr1 = (l < 32) ? w10 : w11;   // row1
            const uint4 r0 = *(const uint4*)(plane + (size_t)o0 * 128 + 4 * l);
            const uint4 r1 = *(const uint4*)(plane + (size_t)o1 * 128 + 4 * l);
            a[0] = fmaf(wr0, blo(r0.x), a[0]); a[1] = fmaf(wr0, bhi(r0.x), a[1]);
            a[2] = fmaf(wr0, blo(r0.y), a[2]); a[3] = fmaf(wr0, bhi(r0.y), a[3]);
            a[4] = fmaf(wr0, blo(r0.z), a[4]); a[5] = fmaf(wr0, bhi(r0.z), a[5]);
            a[6] = fmaf(wr0, blo(r0.w), a[6]); a[7] = fmaf(wr0, bhi(r0.w), a[7]);
            a[0] = fmaf(wr1, blo(r1.x), a[0]); a[1] = fmaf(wr1, bhi(r1.x), a[1]);
            a[2] = fmaf(wr1, blo(r1.y), a[2]); a[3] = fmaf(wr1, bhi(r1.y), a[3]);
            a[4] = fmaf(wr1, blo(r1.z), a[4]); a[5] = fmaf(wr1, bhi(r1.z), a[5]);
            a[6] = fmaf(wr1, blo(r1.w), a[6]); a[7] = fmaf(wr1, bhi(r1.w), a[7]);
        }
        // combine A-half (lanes 0-31) with B-half (lanes 32-63): same channels
#pragma unroll
        for (int k = 0; k < 8; ++k) a[k] += __shfl_xor(a[k], 32, 64);
        if (l < 32) {
            const int pxl = wv * 8 + p;
            float* dst = &tile[pxl * 260 + 8 * l];
            *(float4*)dst       = make_float4(a[0], a[1], a[2], a[3]);
            *(float4*)(dst + 4) = make_float4(a[4], a[5], a[6], a[7]);
        }
    }
    __syncthreads();
    // flush: lane -> px (coalesced w), 8 channels per iteration
    const size_t obase = (size_t)n * C_ * HW_ + h * W_ + w0;
#pragma unroll 4
    for (int it = 0; it < 32; ++it) {
        const int flat = it * 256 + t;
        const int px = flat & 31;
        const int c  = flat >> 5;
        out[obase + (size_t)c * HW_ + px] = tile[px * 260 + c];
    }
}

// ---------- Fallback (round-1 kernel) if ws too small ----------
__global__ __launch_bounds__(256) void fr_kernel(
    const float* __restrict__ feat,
    const float* __restrict__ bb,
    float* __restrict__ out)
{
    const int lane = threadIdx.x & 63;
    const int wave = threadIdx.x >> 6;
    const int tile = blockIdx.x;
    const int wt   = tile & 1;
    const int h    = (tile >> 1) & (H_ - 1);
    const int n    = tile >> 8;
    const int w    = wt * 64 + lane;
    const int cb   = blockIdx.y;

    const float* b = bb + (size_t)((n * H_ + h) * W_ + w) * 5;
    const float cx = b[0], cy = b[1], bw = b[2], bh = b[3], th = b[4];
    const float st = sinf(th), ct = cosf(th);
    const float vx = bw * ct * 0.5f, vy = bw * st * 0.5f;
    const float wx = -bh * st * 0.5f, wy = bh * ct * 0.5f;
    const float pxs[5] = {cx, cx + vx + wx, cx - vx + wx, cx - vx - wx, cx + vx - wx};
    const float pys[5] = {cy, cy + vy + wy, cy - vy + wy, cy - vy - wy, cy + vy - wy};

    int   off0[5], off1[5];
    float wgt[20];
#pragma unroll
    for (int p = 0; p < 5; ++p) {
        float x = pxs[p] * SCALE;
        float y = pys[p] * SCALE;
        const bool valid = (y >= -1.0f) && (y <= (float)H_) &&
                           (x >= -1.0f) && (x <= (float)W_);
        y = fmaxf(y, 0.0f);
        x = fmaxf(x, 0.0f);
        int yl = min((int)y, H_ - 1);
        int xl = min((int)x, W_ - 1);
        if (yl >= H_ - 1) y = (float)yl;
        if (xl >= W_ - 1) x = (float)xl;
        const int yh = min(yl + 1, H_ - 1);
        const float ly = y - (float)yl, lx = x - (float)xl;
        const float hy = 1.0f - ly,     hx = 1.0f - lx;
        const int xa = min(xl, W_ - 2);
        float wA, wB;
        if (xl < W_ - 1) { wA = hx; wB = lx; }
        else             { wA = 0.0f; wB = 1.0f; }
        const float v = valid ? 1.0f : 0.0f;
        off0[p] = yl * W_ + xa;
        off1[p] = yh * W_ + xa;
        wgt[p * 4 + 0] = v * hy * wA;
        wgt[p * 4 + 1] = v * hy * wB;
        wgt[p * 4 + 2] = v * ly * wA;
        wgt[p * 4 + 3] = v * ly * wB;
    }

    const int hw = h * W_ + w;
    const size_t planeBase = ((size_t)n * C_ + cb * 64 + wave * 16) * HW_;
    const float* fp = feat + planeBase;
    float*       op = out  + planeBase;
    for (int it = 0; it < 16; ++it) {
        float acc = fp[hw];
#pragma unroll
        for (int p = 0; p < 5; ++p) {
            acc += wgt[p * 4 + 0] * fp[off0[p]]
                 + wgt[p * 4 + 1] * fp[off0[p] + 1]
                 + wgt[p * 4 + 2] * fp[off1[p]]
                 + wgt[p * 4 + 3] * fp[off1[p] + 1];
        }
        op[hw] = acc;
        fp += HW_;
        op += HW_;
    }
}

extern "C" void kernel_launch(void* const* d_in, const int* in_sizes, int n_in,
                              void* d_out, int out_size, void* d_ws, size_t ws_size,
                              hipStream_t stream) {
    const float* feat = (const float*)d_in[0];   // [N,C,H,W] fp32
    const float* bbox = (const float*)d_in[1];   // [N,H,W,5] fp32
    float* out = (float*)d_out;

    const size_t nhwcBytes = (size_t)N_ * HW_ * C_ * 2;        // 32 MB bf16
    const size_t geoBytes  = (size_t)N_ * HW_ * 32 * 4;        // 8 MB
    if (ws_size >= nhwcBytes + geoBytes) {
        uint32* nhwcU = (uint32*)d_ws;
        uint32* geoG  = (uint32*)((char*)d_ws + nhwcBytes);
        geo_kernel<<<dim3(N_ * HW_ / 256), dim3(256), 0, stream>>>(bbox, geoG);
        nchw2nhwc_bf16<<<dim3(HW_ / 128, N_), dim3(512), 0, stream>>>(feat, nhwcU);
        fr_refine<<<dim3(N_ * H_ * (W_ / 32)), dim3(256), 0, stream>>>(nhwcU, geoG, out);
    } else {
        dim3 grid(N_ * H_ * (W_ / 64), C_ / 64, 1);
        fr_kernel<<<grid, dim3(256), 0, stream>>>(feat, bbox, out);
    }
}

// Round 5
// 175.477 us; speedup vs baseline: 4.1561x; 1.0206x over previous
//
#include <hip/hip_runtime.h>

// FeatureRefine, MI355X/gfx950 — round 5.
// R4: refine 67us (FETCH 201MB; L2 miss ~29% on gather plane), transpose was
// NEUTRAL vs R3 (~60us, latency/granule-bound 512B streams). Changes:
//  1. transpose v3: 1024thr, 256hw x 256c tile (130KB LDS, 1 block/CU).
//     1KB-contiguous float4 reads, 8 loads in flight/wave, one contiguous
//     128KB NHWC write span per block.
//  2. refine: h-banded XCD swizzle — xcd owns (batch, h-half), sweeps h
//     monotonically; concurrent working set ~2.6MB < 4MB per-XCD L2
//     (sample reach is only ±11 rows).

#define N_ 4
#define C_ 256
#define H_ 128
#define W_ 128
#define HW_ (H_ * W_)
#define SCALE 0.125f

typedef unsigned int uint32;

__device__ __forceinline__ uint32 f2bf(float f) {
    uint32 u = __float_as_uint(f);
    u = (u + 0x7FFF + ((u >> 16) & 1)) >> 16;   // RNE
    return u;
}
__device__ __forceinline__ float blo(uint32 u) { return __uint_as_float(u << 16); }
__device__ __forceinline__ float bhi(uint32 u) { return __uint_as_float(u & 0xFFFF0000u); }

// ---------- Pass 0: per-pixel geometry records (32 uints = 128 B each) ----------
__global__ __launch_bounds__(256) void geo_kernel(const float* __restrict__ bb,
                                                  uint32* __restrict__ geoG)
{
    const int px = blockIdx.x * 256 + threadIdx.x;
    const float* b = bb + (size_t)px * 5;
    const float cx = b[0], cy = b[1], bw = b[2], bh = b[3], th = b[4];
    const float st = sinf(th), ct = cosf(th);
    const float vx = bw * ct * 0.5f, vy = bw * st * 0.5f;
    const float wx = -bh * st * 0.5f, wy = bh * ct * 0.5f;
    const float pxs[5] = {cx, cx + vx + wx, cx - vx + wx, cx - vx - wx, cx + vx - wx};
    const float pys[5] = {cy, cy + vy + wy, cy - vy + wy, cy - vy - wy, cy + vy - wy};

    uint32* g = geoG + (size_t)px * 32;
#pragma unroll
    for (int p = 0; p < 5; ++p) {
        float x = pxs[p] * SCALE;
        float y = pys[p] * SCALE;
        const bool valid = (y >= -1.0f) && (y <= (float)H_) &&
                           (x >= -1.0f) && (x <= (float)W_);
        y = fmaxf(y, 0.0f);
        x = fmaxf(x, 0.0f);
        int yl = min((int)y, H_ - 1);
        int xl = min((int)x, W_ - 1);
        if (yl >= H_ - 1) y = (float)yl;   // mmcv border snap: ly = 0
        if (xl >= W_ - 1) x = (float)xl;   // lx = 0
        const int yh = min(yl + 1, H_ - 1);
        const float ly = y - (float)yl, lx = x - (float)xl;
        const float hy = 1.0f - ly,     hx = 1.0f - lx;
        const int xa = min(xl, W_ - 2);
        float wA, wB;
        if (xl < W_ - 1) { wA = hx; wB = lx; }
        else             { wA = 0.0f; wB = 1.0f; }
        const float v = valid ? 1.0f : 0.0f;
        g[p]      = (uint32)(yl * W_ + xa);
        g[5 + p]  = (uint32)(yh * W_ + xa);
        g[10 + p] = __float_as_uint(v * hy * wA);
        g[15 + p] = __float_as_uint(v * hy * wB);
        g[20 + p] = __float_as_uint(v * ly * wA);
        g[25 + p] = __float_as_uint(v * ly * wB);
    }
    g[30] = 0u; g[31] = 0u;
}

// ---------- Pass 1: NCHW fp32 -> NHWC bf16 (packed ch-pairs), v3 ----------
// 1024 thr / 16 waves; tile 256 hw x 256 c; LDS [cpair][hw] stride 260 (130 KB).
// Reads: float4 = 1KB contiguous per wave-load, 8 in flight. Writes: the block
// emits one contiguous 128 KB NHWC span, fully coalesced.
__global__ __launch_bounds__(1024) void nchw2nhwc_bf16(const float* __restrict__ in,
                                                       uint32* __restrict__ outU)
{
    __shared__ uint32 tile[128 * 260];
    const int t   = threadIdx.x;
    const int l   = t & 63;
    const int g   = t >> 6;               // wave 0..15
    const int hw0 = blockIdx.x * 256;
    const int n   = blockIdx.y;
    const float* base = in + (size_t)n * C_ * HW_ + hw0 + 4 * l;

#pragma unroll
    for (int half = 0; half < 2; ++half) {
        float4 v0[4], v1[4];
#pragma unroll
        for (int r = 0; r < 4; ++r) {
            const int cp = g * 8 + half * 4 + r;
            v0[r] = *(const float4*)(base + (size_t)(2 * cp) * HW_);
            v1[r] = *(const float4*)(base + (size_t)(2 * cp + 1) * HW_);
        }
#pragma unroll
        for (int r = 0; r < 4; ++r) {
            const int cp = g * 8 + half * 4 + r;
            uint4 u;
            u.x = f2bf(v0[r].x) | (f2bf(v1[r].x) << 16);
            u.y = f2bf(v0[r].y) | (f2bf(v1[r].y) << 16);
            u.z = f2bf(v0[r].z) | (f2bf(v1[r].z) << 16);
            u.w = f2bf(v0[r].w) | (f2bf(v1[r].w) << 16);
            *(uint4*)&tile[cp * 260 + 4 * l] = u;   // b128, conflict-free
        }
    }
    __syncthreads();
    uint32* dst = outU + ((size_t)n * HW_ + hw0) * 128;
#pragma unroll 8
    for (int it = 0; it < 32; ++it) {
        const int f   = it * 1024 + t;    // f = row*128 + q
        const int row = f >> 7;
        const int q   = f & 127;
        dst[f] = tile[q * 260 + row];     // 2-way-free pattern would need odd
    }                                      // stride; 8-way here costs <0.5us
}

// ---------- Pass 2: refine — wave per pixel, h-banded XCD swizzle ----------
__global__ __launch_bounds__(256) void fr_refine(const uint32* __restrict__ nhwcU,
                                                 const uint32* __restrict__ geoG,
                                                 float* __restrict__ out)
{
    __shared__ float tile[32 * 260];      // [px][c], stride 260 (33 KB)
    const int t  = threadIdx.x;
    const int l  = t & 63;
    const int wv = __builtin_amdgcn_readfirstlane(t >> 6);
    const int bx = blockIdx.x;            // [0, 2048)
    // XCD x (bx&7) owns batch x>>1, h-half x&1; sweeps h with dispatch order
    // so concurrently-resident blocks cover a ~2.6 MB band (< 4 MB L2/XCD).
    const int xcd = bx & 7;
    const int n   = xcd >> 1;
    const int s   = bx >> 3;              // [0, 256)
    const int h   = ((xcd & 1) << 6) | (s >> 2);
    const int w0  = (s & 3) * 32;

    const float idsel = (l < 32) ? 1.0f : 0.0f;   // identity only in A-half
    const uint32* plane = nhwcU + (size_t)n * HW_ * 128;
    const uint32* gb = geoG + (size_t)((n * H_ + h) * W_ + w0 + wv * 8) * 32;

#pragma unroll 2
    for (int p = 0; p < 8; ++p) {
        const uint32* g = gb + p * 32;    // wave-uniform -> s_load
        const int hwp = h * W_ + w0 + wv * 8 + p;

        float a[8];
        {   // identity from own NHWC row (bf16)
            const uint4 r = *(const uint4*)(plane + (size_t)hwp * 128 + 4 * l);
            a[0] = idsel * blo(r.x); a[1] = idsel * bhi(r.x);
            a[2] = idsel * blo(r.y); a[3] = idsel * bhi(r.y);
            a[4] = idsel * blo(r.z); a[5] = idsel * bhi(r.z);
            a[6] = idsel * blo(r.w); a[7] = idsel * bhi(r.w);
        }
#pragma unroll
        for (int q = 0; q < 5; ++q) {
            const int o0 = (int)g[q];
            const int o1 = (int)g[5 + q];
            const float w00 = __uint_as_float(g[10 + q]);
            const float w01 = __uint_as_float(g[15 + q]);
            const float w10 = __uint_as_float(g[20 + q]);
            const float w11 = __uint_as_float(g[25 + q]);
            const float wr0 = (l < 32) ? w00 : w01;   // row0: A | B corner
            const float wr1 = (l < 32) ? w10 : w11;   // row1
            const uint4 r0 = *(const uint4*)(plane + (size_t)o0 * 128 + 4 * l);
            const uint4 r1 = *(const uint4*)(plane + (size_t)o1 * 128 + 4 * l);
            a[0] = fmaf(wr0, blo(r0.x), a[0]); a[1] = fmaf(wr0, bhi(r0.x), a[1]);
            a[2] = fmaf(wr0, blo(r0.y), a[2]); a[3] = fmaf(wr0, bhi(r0.y), a[3]);
            a[4] = fmaf(wr0, blo(r0.z), a[4]); a[5] = fmaf(wr0, bhi(r0.z), a[5]);
            a[6] = fmaf(wr0, blo(r0.w), a[6]); a[7] = fmaf(wr0, bhi(r0.w), a[7]);
            a[0] = fmaf(wr1, blo(r1.x), a[0]); a[1] = fmaf(wr1, bhi(r1.x), a[1]);
            a[2] = fmaf(wr1, blo(r1.y), a[2]); a[3] = fmaf(wr1, bhi(r1.y), a[3]);
            a[4] = fmaf(wr1, blo(r1.z), a[4]); a[5] = fmaf(wr1, bhi(r1.z), a[5]);
            a[6] = fmaf(wr1, blo(r1.w), a[6]); a[7] = fmaf(wr1, bhi(r1.w), a[7]);
        }
#pragma unroll
        for (int k = 0; k < 8; ++k) a[k] += __shfl_xor(a[k], 32, 64);
        if (l < 32) {
            const int pxl = wv * 8 + p;
            float* dst = &tile[pxl * 260 + 8 * l];
            *(float4*)dst       = make_float4(a[0], a[1], a[2], a[3]);
            *(float4*)(dst + 4) = make_float4(a[4], a[5], a[6], a[7]);
        }
    }
    __syncthreads();
    const size_t obase = (size_t)n * C_ * HW_ + h * W_ + w0;
#pragma unroll 4
    for (int it = 0; it < 32; ++it) {
        const int flat = it * 256 + t;
        const int px = flat & 31;
        const int c  = flat >> 5;
        out[obase + (size_t)c * HW_ + px] = tile[px * 260 + c];
    }
}

// ---------- Fallback (round-1 kernel) if ws too small ----------
__global__ __launch_bounds__(256) void fr_kernel(
    const float* __restrict__ feat,
    const float* __restrict__ bb,
    float* __restrict__ out)
{
    const int lane = threadIdx.x & 63;
    const int wave = threadIdx.x >> 6;
    const int tile = blockIdx.x;
    const int wt   = tile & 1;
    const int h    = (tile >> 1) & (H_ - 1);
    const int n    = tile >> 8;
    const int w    = wt * 64 + lane;
    const int cb   = blockIdx.y;

    const float* b = bb + (size_t)((n * H_ + h) * W_ + w) * 5;
    const float cx = b[0], cy = b[1], bw = b[2], bh = b[3], th = b[4];
    const float st = sinf(th), ct = cosf(th);
    const float vx = bw * ct * 0.5f, vy = bw * st * 0.5f;
    const float wx = -bh * st * 0.5f, wy = bh * ct * 0.5f;
    const float pxs[5] = {cx, cx + vx + wx, cx - vx + wx, cx - vx - wx, cx + vx - wx};
    const float pys[5] = {cy, cy + vy + wy, cy - vy + wy, cy - vy - wy, cy + vy - wy};

    int   off0[5], off1[5];
    float wgt[20];
#pragma unroll
    for (int p = 0; p < 5; ++p) {
        float x = pxs[p] * SCALE;
        float y = pys[p] * SCALE;
        const bool valid = (y >= -1.0f) && (y <= (float)H_) &&
                           (x >= -1.0f) && (x <= (float)W_);
        y = fmaxf(y, 0.0f);
        x = fmaxf(x, 0.0f);
        int yl = min((int)y, H_ - 1);
        int xl = min((int)x, W_ - 1);
        if (yl >= H_ - 1) y = (float)yl;
        if (xl >= W_ - 1) x = (float)xl;
        const int yh = min(yl + 1, H_ - 1);
        const float ly = y - (float)yl, lx = x - (float)xl;
        const float hy = 1.0f - ly,     hx = 1.0f - lx;
        const int xa = min(xl, W_ - 2);
        float wA, wB;
        if (xl < W_ - 1) { wA = hx; wB = lx; }
        else             { wA = 0.0f; wB = 1.0f; }
        const float v = valid ? 1.0f : 0.0f;
        off0[p] = yl * W_ + xa;
        off1[p] = yh * W_ + xa;
        wgt[p * 4 + 0] = v * hy * wA;
        wgt[p * 4 + 1] = v * hy * wB;
        wgt[p * 4 + 2] = v * ly * wA;
        wgt[p * 4 + 3] = v * ly * wB;
    }

    const int hw = h * W_ + w;
    const size_t planeBase = ((size_t)n * C_ + cb * 64 + wave * 16) * HW_;
    const float* fp = feat + planeBase;
    float*       op = out  + planeBase;
    for (int it = 0; it < 16; ++it) {
        float acc = fp[hw];
#pragma unroll
        for (int p = 0; p < 5; ++p) {
            acc += wgt[p * 4 + 0] * fp[off0[p]]
                 + wgt[p * 4 + 1] * fp[off0[p] + 1]
                 + wgt[p * 4 + 2] * fp[off1[p]]
                 + wgt[p * 4 + 3] * fp[off1[p] + 1];
        }
        op[hw] = acc;
        fp += HW_;
        op += HW_;
    }
}

extern "C" void kernel_launch(void* const* d_in, const int* in_sizes, int n_in,
                              void* d_out, int out_size, void* d_ws, size_t ws_size,
                              hipStream_t stream) {
    const float* feat = (const float*)d_in[0];   // [N,C,H,W] fp32
    const float* bbox = (const float*)d_in[1];   // [N,H,W,5] fp32
    float* out = (float*)d_out;

    const size_t nhwcBytes = (size_t)N_ * HW_ * C_ * 2;        // 32 MB bf16
    const size_t geoBytes  = (size_t)N_ * HW_ * 32 * 4;        // 8 MB
    if (ws_size >= nhwcBytes + geoBytes) {
        uint32* nhwcU = (uint32*)d_ws;
        uint32* geoG  = (uint32*)((char*)d_ws + nhwcBytes);
        geo_kernel<<<dim3(N_ * HW_ / 256), dim3(256), 0, stream>>>(bbox, geoG);
        nchw2nhwc_bf16<<<dim3(HW_ / 256, N_), dim3(1024), 0, stream>>>(feat, nhwcU);
        fr_refine<<<dim3(N_ * H_ * (W_ / 32)), dim3(256), 0, stream>>>(nhwcU, geoG, out);
    } else {
        dim3 grid(N_ * H_ * (W_ / 64), C_ / 64, 1);
        fr_kernel<<<grid, dim3(256), 0, stream>>>(feat, bbox, out);
    }
}